// Round 1
// baseline (549.901 us; speedup 1.0000x reference)
//
#include <hip/hip_runtime.h>
#include <math.h>

// Problem constants
#define NBT   512      // B*T = 16*32
#define NF    256      // FL = FA = FO
#define NC    768      // C
#define NROW  64       // L = A
#define NORG  16       // O
#define NE    128      // EL = EA = EO

// ws byte offsets
#define WS_LAB_CB   0
#define WS_LAB_ADD  131072
#define WS_ABN_CB   262144
#define WS_WCNT     393216   // 64*16 f32
#define WS_INVL     397312   // 16 f32
#define WS_INVA     397376
#define WS_MASK     397440
#define WS_LRS      397504   // 65 int (padded to 384B)
#define WS_LRE      397888   // 128 int
#define WS_LRO      398400
#define WS_ARS      398912
#define WS_ARE      399296
#define WS_ARO      399808

// ---------------------------------------------------------------------------
// PK1: tiny metadata kernel — degrees, row-sorted edge lists, o2a weights.
// ---------------------------------------------------------------------------
__global__ void pk_meta(const int* __restrict__ lab_idx, const int* __restrict__ lab_org_idx,
                        const int* __restrict__ abn_idx, const int* __restrict__ abn_org_idx,
                        const int* __restrict__ o2a_abn_idx, const int* __restrict__ o2a_org_idx,
                        char* __restrict__ ws) {
    __shared__ int cL[NORG], cA[NORG], cC[NROW * NORG];
    __shared__ int cRL[NROW], cRA[NROW];
    __shared__ int sL[NROW + 1], sA[NROW + 1];
    __shared__ int curL[NROW], curA[NROW];
    const int t = threadIdx.x;   // block = 128 threads
    for (int i = t; i < NROW * NORG; i += 128) cC[i] = 0;
    if (t < NORG) { cL[t] = 0; cA[t] = 0; }
    if (t < NROW) { cRL[t] = 0; cRA[t] = 0; }
    __syncthreads();
    atomicAdd(&cL[lab_org_idx[t]], 1);
    atomicAdd(&cA[abn_org_idx[t]], 1);
    atomicAdd(&cC[o2a_abn_idx[t] * NORG + o2a_org_idx[t]], 1);
    atomicAdd(&cRL[lab_idx[t]], 1);
    atomicAdd(&cRA[abn_idx[t]], 1);
    __syncthreads();
    if (t == 0) { int s = 0; for (int r = 0; r < NROW; ++r) { sL[r] = s; s += cRL[r]; } sL[NROW] = s; }
    if (t == 1) { int s = 0; for (int r = 0; r < NROW; ++r) { sA[r] = s; s += cRA[r]; } sA[NROW] = s; }
    __syncthreads();
    if (t < NROW) { curL[t] = sL[t]; curA[t] = sA[t]; }
    __syncthreads();
    int* lre = (int*)(ws + WS_LRE); int* lro = (int*)(ws + WS_LRO);
    int* are = (int*)(ws + WS_ARE); int* aro = (int*)(ws + WS_ARO);
    {
        int p = atomicAdd(&curL[lab_idx[t]], 1);
        lre[p] = t; lro[p] = lab_org_idx[t];
        int q = atomicAdd(&curA[abn_idx[t]], 1);
        are[q] = t; aro[q] = abn_org_idx[t];
    }
    __syncthreads();
    float* invL = (float*)(ws + WS_INVL);
    float* invA = (float*)(ws + WS_INVA);
    float* mskF = (float*)(ws + WS_MASK);
    if (t < NORG) {
        invL[t] = cL[t] > 0 ? 1.0f / (float)cL[t] : 0.0f;
        invA[t] = cA[t] > 0 ? 1.0f / (float)cA[t] : 0.0f;
        mskF[t] = (cL[t] > 0 || cA[t] > 0) ? 1.0f : 0.0f;
    }
    if (t < NROW + 1) {
        ((int*)(ws + WS_LRS))[t] = sL[t];
        ((int*)(ws + WS_ARS))[t] = sA[t];
    }
    float* wcnt = (float*)(ws + WS_WCNT);
    if (t < NROW) {
        int dega = 0;
        for (int o = 0; o < NORG; ++o) dega += cC[t * NORG + o];
        float inv = 1.0f / (float)(dega > 1 ? dega : 1);
        for (int o = 0; o < NORG; ++o) wcnt[t * NORG + o] = (float)cC[t * NORG + o] * inv;
    }
}

// ---------------------------------------------------------------------------
// PK2: per-edge bias tables (b,t-independent K=768 dots).
//   lab_cb[e][g]  = (lab_concept[lab_idx[e]] + lab_rel[e]) @ W_lab[256:] + b_lab
//   lab_add[e][g] = lab_rel[e] @ D
//   abn_cb[e][g]  = (abn_concept[abn_idx[e]] + abn_rel[e]) @ W_abn[256:] + b_abn
// ---------------------------------------------------------------------------
__global__ void pk_bias(const float* __restrict__ lab_concept, const float* __restrict__ abn_concept,
                        const float* __restrict__ lab_rel, const float* __restrict__ abn_rel,
                        const float* __restrict__ W_lab, const float* __restrict__ b_lab,
                        const float* __restrict__ W_abn, const float* __restrict__ b_abn,
                        const float* __restrict__ D,
                        const int* __restrict__ lab_idx, const int* __restrict__ abn_idx,
                        char* __restrict__ ws) {
    const int e2 = blockIdx.x;
    const int g = threadIdx.x;
    if (e2 < NE) {
        const int e = e2;
        const float* rel = lab_rel + e * NC;
        const float* con = lab_concept + lab_idx[e] * NC;
        float a1 = b_lab[g], a2 = 0.0f;
        #pragma unroll 4
        for (int c = 0; c < NC; ++c) {
            float r = rel[c];
            float ce = con[c] + r;
            a1 += ce * W_lab[(NF + c) * NF + g];
            a2 += r * D[c * NF + g];
        }
        ((float*)(ws + WS_LAB_CB))[e * NF + g] = a1;
        ((float*)(ws + WS_LAB_ADD))[e * NF + g] = a2;
    } else {
        const int e = e2 - NE;
        const float* rel = abn_rel + e * NC;
        const float* con = abn_concept + abn_idx[e] * NC;
        float a1 = b_abn[g];
        #pragma unroll 4
        for (int c = 0; c < NC; ++c) {
            float ce = con[c] + rel[c];
            a1 += ce * W_abn[(NF + c) * NF + g];
        }
        ((float*)(ws + WS_ABN_CB))[e * NF + g] = a1;
    }
}

// ---------------------------------------------------------------------------
// Main per-(b,t) fused kernel.
// ---------------------------------------------------------------------------

// 64x256x256 fp32 GEMM (8x8 register tile) with fused edge-scatter epilogue:
//   for each edge with row == r: atomically add (tanh(Y[r][c]+cb[e][c]) (+ add[e][c])) * invD[org]
//   into sAcc[org][c].
template <bool HASADD>
__device__ __forceinline__ void gemm_edge(
    const float* __restrict__ X, const float* __restrict__ W,
    const float* __restrict__ cb, const float* __restrict__ addt,
    const float* __restrict__ invD,
    const int* __restrict__ rs, const int* __restrict__ re, const int* __restrict__ ro,
    float* __restrict__ sAcc, float* __restrict__ sXt, float* __restrict__ sWt, int tid) {
    const int tr = tid >> 5;          // 0..7  -> rows tr*8..+8
    const int tc = tid & 31;          // 0..31 -> cols tc*8..+8
    const int lr = tid & 63;          // X stage: row
    const int lk = (tid >> 6) * 8;    // X stage: k chunk (wave-uniform)
    const int wk = tid & 31;          // W stage: row in tile
    const int wc = (tid >> 5) * 32;   // W stage: col chunk

    float acc[8][8];
    #pragma unroll
    for (int i = 0; i < 8; ++i)
        #pragma unroll
        for (int j = 0; j < 8; ++j) acc[i][j] = 0.0f;

    for (int k0 = 0; k0 < NF; k0 += 32) {
        float xv[8];
        *(float4*)(xv)     = *(const float4*)(X + lr * NF + k0 + lk);
        *(float4*)(xv + 4) = *(const float4*)(X + lr * NF + k0 + lk + 4);
        float4 wv[8];
        const float* Wp = W + (k0 + wk) * NF + wc;
        #pragma unroll
        for (int q = 0; q < 8; ++q) wv[q] = *(const float4*)(Wp + 4 * q);
        __syncthreads();  // previous tile's compute done before overwrite
        #pragma unroll
        for (int n = 0; n < 8; ++n) sXt[(lk + n) * 64 + lr] = xv[n];  // transposed [k][r]
        float* wd = sWt + wk * 260 + wc;                               // padded stride 260
        #pragma unroll
        for (int q = 0; q < 8; ++q) *(float4*)(wd + 4 * q) = wv[q];
        __syncthreads();
        #pragma unroll
        for (int k = 0; k < 32; ++k) {
            float a[8], b[8];
            #pragma unroll
            for (int i = 0; i < 8; ++i) a[i] = sXt[k * 64 + tr * 8 + i];
            #pragma unroll
            for (int j = 0; j < 8; ++j) b[j] = sWt[k * 260 + tc * 8 + j];
            #pragma unroll
            for (int i = 0; i < 8; ++i)
                #pragma unroll
                for (int j = 0; j < 8; ++j) acc[i][j] += a[i] * b[j];
        }
    }

    // fused edge epilogue (avg 2 edges/row)
    #pragma unroll
    for (int i = 0; i < 8; ++i) {
        const int r = tr * 8 + i;
        const int s0 = rs[r], s1 = rs[r + 1];
        for (int ii = s0; ii < s1; ++ii) {
            const int ed = re[ii];
            const int o = ro[ii];
            const float sc = invD[o];
            float cbl[8];
            const float* cbp = cb + ed * NF + tc * 8;
            *(float4*)(cbl)     = *(const float4*)(cbp);
            *(float4*)(cbl + 4) = *(const float4*)(cbp + 4);
            float adl[8];
            if (HASADD) {
                const float* ap = addt + ed * NF + tc * 8;
                *(float4*)(adl)     = *(const float4*)(ap);
                *(float4*)(adl + 4) = *(const float4*)(ap + 4);
            }
            #pragma unroll
            for (int j = 0; j < 8; ++j) {
                float v = tanhf(acc[i][j] + cbl[j]);
                if (HASADD) v += adl[j];
                atomicAdd(&sAcc[o * NF + tc * 8 + j], v * sc);
            }
        }
    }
}

// 16x256x256 GEMM: sOut[r][c] = post( sum_k sIn[r][k]*Wg[k][c] + bias[c] )
template <bool DOTANH>
__device__ __forceinline__ void small_gemm16(
    const float* __restrict__ sIn, const float* __restrict__ Wg,
    const float* __restrict__ bias, const float* __restrict__ mk,
    float* __restrict__ sOut, int tid) {
    const int tr = tid >> 5;        // 0..7 -> rows 2tr, 2tr+1
    const int tc = tid & 31;        // cols tc*8..+8
    const int r0 = tr * 2, r1 = r0 + 1;
    float a0c[8], a1c[8];
    #pragma unroll
    for (int j = 0; j < 8; ++j) { a0c[j] = 0.0f; a1c[j] = 0.0f; }
    #pragma unroll 4
    for (int k = 0; k < NF; ++k) {
        const float a0 = sIn[r0 * NF + k];
        const float a1 = sIn[r1 * NF + k];
        float bb[8];
        const float* wp = Wg + k * NF + tc * 8;
        *(float4*)(bb)     = *(const float4*)(wp);
        *(float4*)(bb + 4) = *(const float4*)(wp + 4);
        #pragma unroll
        for (int j = 0; j < 8; ++j) { a0c[j] += a0 * bb[j]; a1c[j] += a1 * bb[j]; }
    }
    float bv[8];
    *(float4*)(bv)     = *(const float4*)(bias + tc * 8);
    *(float4*)(bv + 4) = *(const float4*)(bias + tc * 8 + 4);
    const float m0 = mk ? mk[r0] : 1.0f;
    const float m1 = mk ? mk[r1] : 1.0f;
    #pragma unroll
    for (int j = 0; j < 8; ++j) {
        float v0 = a0c[j] + bv[j];
        float v1 = a1c[j] + bv[j];
        if (DOTANH) { v0 = tanhf(v0); v1 = tanhf(v1); }
        sOut[r0 * NF + tc * 8 + j] = v0 * m0;
        sOut[r1 * NF + tc * 8 + j] = v1 * m1;
    }
}

__global__ __launch_bounds__(256, 2) void kg_main(
    const float* __restrict__ lab_feats, const float* __restrict__ abn_feats,
    const float* __restrict__ W_lab, const float* __restrict__ W_abn,
    const float* __restrict__ W_org, const float* __restrict__ b_org,
    const float* __restrict__ W_o2a, const float* __restrict__ b_o2a,
    const char* __restrict__ ws, float* __restrict__ out) {
    // LDS: 16K + 8K + 33.3K = 57.9 KB -> 2 blocks/CU
    __shared__ float sAcc[NORG * NF];   // organ accumulator m[o][g]; later msg
    __shared__ float sXt[32 * 64];      // X k-tile (transposed); later w_cnt copy
    __shared__ float sWt[32 * 260];     // W k-tile (padded); later organ_states

    const int tid = threadIdx.x;
    const int bt = blockIdx.x;

    const float* lab_cb  = (const float*)(ws + WS_LAB_CB);
    const float* lab_add = (const float*)(ws + WS_LAB_ADD);
    const float* abn_cb  = (const float*)(ws + WS_ABN_CB);
    const float* wcnt    = (const float*)(ws + WS_WCNT);
    const float* invL    = (const float*)(ws + WS_INVL);
    const float* invA    = (const float*)(ws + WS_INVA);
    const float* mskF    = (const float*)(ws + WS_MASK);
    const int* lrs = (const int*)(ws + WS_LRS);
    const int* lre = (const int*)(ws + WS_LRE);
    const int* lro = (const int*)(ws + WS_LRO);
    const int* ars = (const int*)(ws + WS_ARS);
    const int* are = (const int*)(ws + WS_ARE);
    const int* aro = (const int*)(ws + WS_ARO);

    for (int i = tid; i < NORG * NF; i += 256) sAcc[i] = 0.0f;
    // (first barrier inside gemm_edge orders this zeroing before any atomics)

    const float* Xl = lab_feats + bt * (NROW * NF);
    const float* Xa = abn_feats + bt * (NROW * NF);

    gemm_edge<true >(Xl, W_lab, lab_cb, lab_add, invL, lrs, lre, lro, sAcc, sXt, sWt, tid);
    gemm_edge<false>(Xa, W_abn, abn_cb, nullptr, invA, ars, are, aro, sAcc, sXt, sWt, tid);
    __syncthreads();  // all scatter atomics done; sXt/sWt free

    // stage o2a weights into free LDS
    for (int i = tid; i < NROW * NORG; i += 256) sXt[i] = wcnt[i];

    // organ_states = tanh(m @ W_org + b_org) * mask  -> sWt
    small_gemm16<true>(sAcc, W_org, b_org, mskF, sWt, tid);
    __syncthreads();
    // msg = states @ W_o2a + b_o2a  -> sAcc
    small_gemm16<false>(sWt, W_o2a, b_o2a, nullptr, sAcc, tid);
    __syncthreads();

    // out[a][g] = abn_feats[a][g] + sum_o wcnt[a][o] * msg[o][g]
    {
        const int g = tid;
        float mr[NORG];
        #pragma unroll
        for (int o = 0; o < NORG; ++o) mr[o] = sAcc[o * NF + g];
        const float* src = abn_feats + bt * (NROW * NF);
        float* dst = out + bt * (NROW * NF);
        for (int a = 0; a < NROW; ++a) {
            float s = 0.0f;
            #pragma unroll
            for (int o = 0; o < NORG; ++o) s += sXt[a * NORG + o] * mr[o];
            dst[a * NF + g] = src[a * NF + g] + s;
        }
    }
}

// ---------------------------------------------------------------------------
extern "C" void kernel_launch(void* const* d_in, const int* in_sizes, int n_in,
                              void* d_out, int out_size, void* d_ws, size_t ws_size,
                              hipStream_t stream) {
    const float* lab_feats   = (const float*)d_in[0];
    const float* abn_feats   = (const float*)d_in[1];
    const float* lab_concept = (const float*)d_in[2];
    const float* abn_concept = (const float*)d_in[3];
    const float* lab_rel     = (const float*)d_in[4];
    const float* abn_rel     = (const float*)d_in[5];
    const float* W_lab       = (const float*)d_in[6];
    const float* b_lab       = (const float*)d_in[7];
    const float* W_abn       = (const float*)d_in[8];
    const float* b_abn       = (const float*)d_in[9];
    const float* W_org       = (const float*)d_in[10];
    const float* b_org       = (const float*)d_in[11];
    const float* D           = (const float*)d_in[12];
    const float* W_o2a       = (const float*)d_in[13];
    const float* b_o2a       = (const float*)d_in[14];
    // d_in[15] = time_mask (all-True by construction), d_in[22] = num_organs (16)
    const int* lab_idx     = (const int*)d_in[16];
    const int* lab_org_idx = (const int*)d_in[17];
    const int* abn_idx     = (const int*)d_in[18];
    const int* abn_org_idx = (const int*)d_in[19];
    const int* o2a_abn_idx = (const int*)d_in[20];
    const int* o2a_org_idx = (const int*)d_in[21];
    char* ws = (char*)d_ws;
    float* out = (float*)d_out;

    pk_meta<<<1, 128, 0, stream>>>(lab_idx, lab_org_idx, abn_idx, abn_org_idx,
                                   o2a_abn_idx, o2a_org_idx, ws);
    pk_bias<<<256, 256, 0, stream>>>(lab_concept, abn_concept, lab_rel, abn_rel,
                                     W_lab, b_lab, W_abn, b_abn, D, lab_idx, abn_idx, ws);
    kg_main<<<NBT, 256, 0, stream>>>(lab_feats, abn_feats, W_lab, W_abn,
                                     W_org, b_org, W_o2a, b_o2a, ws, out);
}

// Round 2
// 394.073 us; speedup vs baseline: 1.3954x; 1.3954x over previous
//
#include <hip/hip_runtime.h>
#include <math.h>

// Problem constants
#define NBT   512      // B*T
#define NF    256      // FL = FA = FO
#define NC    768      // C
#define NROW  64       // L = A
#define NORG  16       // O
#define NE    128      // EL = EA = EO
#define SLD   260      // padded fp32 row stride for 16-row LDS tiles (bank-friendly)

// ---- ws byte offsets -------------------------------------------------------
// bf16 swizzled weight tables (fragment order)
#define WS_SW_LAB1  0         // 256x256  (131072 B) 32-style
#define WS_SW_ABN1  131072    // 256x256
#define WS_SW_LAB2  262144    // 768x256  (393216 B)
#define WS_SW_D     655360    // 768x256
#define WS_SW_ABN2  1048576   // 768x256
#define WS_SW_ORG   1441792   // 256x256  16-style
#define WS_SW_O2A   1572864   // 256x256  16-style
// fp32 per-edge bias tables (bias folded in)
#define WS_LAB_CB   1703936   // 128x256 f32
#define WS_LAB_ADD  1835008
#define WS_ABN_CB   1966080
// metadata
#define WS_WCNT     2097152   // 64x16 f32
#define WS_INVL     2101248   // 16 f32
#define WS_INVA     2101312
#define WS_MASK     2101376
#define WS_LRS      2101440   // 65 int (384B reserved)
#define WS_LRE      2101824   // 128 int (512B)
#define WS_LRO      2102336
#define WS_ARS      2102848
#define WS_ARE      2103232
#define WS_ARO      2103744

typedef __attribute__((ext_vector_type(8)))  short bf16x8;
typedef __attribute__((ext_vector_type(16))) float f32x16;
typedef __attribute__((ext_vector_type(4)))  float f32x4;

__device__ __forceinline__ short f2bf(float f) {
    union { float f; unsigned u; } v; v.f = f;
    unsigned r = v.u + 0x7FFF + ((v.u >> 16) & 1);   // RNE
    return (short)(r >> 16);
}
__device__ __forceinline__ float tanh_fast(float x) {
    float xc = fminf(fmaxf(x, -15.f), 15.f);
    float e = __expf(2.f * xc);
    return 1.f - 2.f / (e + 1.f);
}
__device__ __forceinline__ f32x16 mfma32(bf16x8 a, bf16x8 b, f32x16 c) {
    return __builtin_amdgcn_mfma_f32_32x32x16_bf16(a, b, c, 0, 0, 0);
}
__device__ __forceinline__ f32x4 mfma16(bf16x8 a, bf16x8 b, f32x4 c) {
    return __builtin_amdgcn_mfma_f32_16x16x32_bf16(a, b, c, 0, 0, 0);
}

// ---------------------------------------------------------------------------
// PK0: swizzle all weight matrices to bf16 fragment-order tables in ws.
// 32-style (for 32x32x16 B-frags): slot s -> l=s&63, nt=(s>>6)&7, k16=s>>9;
//   n = nt*32+(l&31), k = k16*16+((l>>5)&1)*8 + j
// 16-style (for 16x16x32 B-frags): l=s&63, nt=(s>>6)&15, k32=s>>10;
//   n = nt*16+(l&15), k = k32*32+((l>>4)&3)*8 + j
// ---------------------------------------------------------------------------
__device__ __forceinline__ void swz32(const float* __restrict__ src, short* __restrict__ dst, int s) {
    const int l = s & 63, rest = s >> 6;
    const int nt = rest & 7, k16 = rest >> 3;
    const int n = nt * 32 + (l & 31);
    const int kb = k16 * 16 + ((l >> 5) & 1) * 8;
    bf16x8 v;
    #pragma unroll
    for (int j = 0; j < 8; ++j) v[j] = f2bf(src[(kb + j) * NF + n]);
    *(bf16x8*)(dst + s * 8) = v;
}
__device__ __forceinline__ void swz16(const float* __restrict__ src, short* __restrict__ dst, int s) {
    const int l = s & 63, rest = s >> 6;
    const int nt = rest & 15, k32 = rest >> 4;
    const int n = nt * 16 + (l & 15);
    const int kb = k32 * 32 + ((l >> 4) & 3) * 8;
    bf16x8 v;
    #pragma unroll
    for (int j = 0; j < 8; ++j) v[j] = f2bf(src[(kb + j) * NF + n]);
    *(bf16x8*)(dst + s * 8) = v;
}

__global__ __launch_bounds__(256) void pk_swz(
    const float* __restrict__ W_lab, const float* __restrict__ W_abn,
    const float* __restrict__ D, const float* __restrict__ W_org,
    const float* __restrict__ W_o2a, char* __restrict__ ws) {
    const int gid = blockIdx.x * 256 + threadIdx.x;
    if      (gid <  8192) swz32(W_lab,            (short*)(ws + WS_SW_LAB1), gid);
    else if (gid < 16384) swz32(W_abn,            (short*)(ws + WS_SW_ABN1), gid - 8192);
    else if (gid < 40960) swz32(W_lab + NF * NF,  (short*)(ws + WS_SW_LAB2), gid - 16384);
    else if (gid < 65536) swz32(D,                (short*)(ws + WS_SW_D),    gid - 40960);
    else if (gid < 90112) swz32(W_abn + NF * NF,  (short*)(ws + WS_SW_ABN2), gid - 65536);
    else if (gid < 98304) swz16(W_org,            (short*)(ws + WS_SW_ORG),  gid - 90112);
    else                  swz16(W_o2a,            (short*)(ws + WS_SW_O2A),  gid - 98304);
}

// ---------------------------------------------------------------------------
// PK1: metadata — degrees, row-sorted edge lists, o2a weights.
// ---------------------------------------------------------------------------
__global__ void pk_meta(const int* __restrict__ lab_idx, const int* __restrict__ lab_org_idx,
                        const int* __restrict__ abn_idx, const int* __restrict__ abn_org_idx,
                        const int* __restrict__ o2a_abn_idx, const int* __restrict__ o2a_org_idx,
                        char* __restrict__ ws) {
    __shared__ int cL[NORG], cA[NORG], cC[NROW * NORG];
    __shared__ int cRL[NROW], cRA[NROW];
    __shared__ int sL[NROW + 1], sA[NROW + 1];
    __shared__ int curL[NROW], curA[NROW];
    const int t = threadIdx.x;   // block = 128 threads
    for (int i = t; i < NROW * NORG; i += 128) cC[i] = 0;
    if (t < NORG) { cL[t] = 0; cA[t] = 0; }
    if (t < NROW) { cRL[t] = 0; cRA[t] = 0; }
    __syncthreads();
    atomicAdd(&cL[lab_org_idx[t]], 1);
    atomicAdd(&cA[abn_org_idx[t]], 1);
    atomicAdd(&cC[o2a_abn_idx[t] * NORG + o2a_org_idx[t]], 1);
    atomicAdd(&cRL[lab_idx[t]], 1);
    atomicAdd(&cRA[abn_idx[t]], 1);
    __syncthreads();
    if (t == 0) { int s = 0; for (int r = 0; r < NROW; ++r) { sL[r] = s; s += cRL[r]; } sL[NROW] = s; }
    if (t == 1) { int s = 0; for (int r = 0; r < NROW; ++r) { sA[r] = s; s += cRA[r]; } sA[NROW] = s; }
    __syncthreads();
    if (t < NROW) { curL[t] = sL[t]; curA[t] = sA[t]; }
    __syncthreads();
    int* lre = (int*)(ws + WS_LRE); int* lro = (int*)(ws + WS_LRO);
    int* are = (int*)(ws + WS_ARE); int* aro = (int*)(ws + WS_ARO);
    {
        int p = atomicAdd(&curL[lab_idx[t]], 1);
        lre[p] = t; lro[p] = lab_org_idx[t];
        int q = atomicAdd(&curA[abn_idx[t]], 1);
        are[q] = t; aro[q] = abn_org_idx[t];
    }
    __syncthreads();
    float* invL = (float*)(ws + WS_INVL);
    float* invA = (float*)(ws + WS_INVA);
    float* mskF = (float*)(ws + WS_MASK);
    if (t < NORG) {
        invL[t] = cL[t] > 0 ? 1.0f / (float)cL[t] : 0.0f;
        invA[t] = cA[t] > 0 ? 1.0f / (float)cA[t] : 0.0f;
        mskF[t] = (cL[t] > 0 || cA[t] > 0) ? 1.0f : 0.0f;
    }
    if (t < NROW + 1) {
        ((int*)(ws + WS_LRS))[t] = sL[t];
        ((int*)(ws + WS_ARS))[t] = sA[t];
    }
    float* wcnt = (float*)(ws + WS_WCNT);
    if (t < NROW) {
        int dega = 0;
        for (int o = 0; o < NORG; ++o) dega += cC[t * NORG + o];
        float inv = 1.0f / (float)(dega > 1 ? dega : 1);
        for (int o = 0; o < NORG; ++o) wcnt[t * NORG + o] = (float)cC[t * NORG + o] * inv;
    }
}

// ---------------------------------------------------------------------------
// PK2: per-edge bias tables via MFMA GEMM, M=128 edges, K=768, N=256.
// grid = 6: (mat 0..2) x (col-half 0..1). Bias folded into cb tables.
// ---------------------------------------------------------------------------
__global__ __launch_bounds__(256) void pk_bias2(
    const float* __restrict__ lab_con, const float* __restrict__ abn_con,
    const float* __restrict__ lab_rel, const float* __restrict__ abn_rel,
    const float* __restrict__ b_lab, const float* __restrict__ b_abn,
    const int* __restrict__ lab_idx, const int* __restrict__ abn_idx,
    char* __restrict__ ws) {
    __shared__ __align__(16) short sAc[1024 * 8];   // 16 KB A k-chunk, frag order
    const int tid = threadIdx.x, l = tid & 63, w = tid >> 6;
    const int mat = blockIdx.x >> 1, h = blockIdx.x & 1;
    const short* Bsw = (const short*)(ws + (mat == 0 ? WS_SW_LAB2 : mat == 1 ? WS_SW_D : WS_SW_ABN2));
    f32x16 acc[4];
    #pragma unroll
    for (int i = 0; i < 4; ++i)
        #pragma unroll
        for (int r = 0; r < 16; ++r) acc[i][r] = 0.f;

    for (int c = 0; c < 12; ++c) {          // K chunks of 64
        __syncthreads();                     // prior chunk's reads done
        #pragma unroll
        for (int ss = 0; ss < 4; ++ss) {
            const int s = tid + 256 * ss;
            const int k16l = s >> 8, rt = (s >> 6) & 3, ll = s & 63;
            const int e = rt * 32 + (ll & 31);
            const int k = c * 64 + k16l * 16 + ((ll >> 5) & 1) * 8;
            float v[8];
            if (mat == 0) {
                const float* cp = lab_con + lab_idx[e] * NC + k;
                const float* rp = lab_rel + e * NC + k;
                #pragma unroll
                for (int j = 0; j < 8; ++j) v[j] = cp[j] + rp[j];
            } else if (mat == 1) {
                const float* rp = lab_rel + e * NC + k;
                #pragma unroll
                for (int j = 0; j < 8; ++j) v[j] = rp[j];
            } else {
                const float* cp = abn_con + abn_idx[e] * NC + k;
                const float* rp = abn_rel + e * NC + k;
                #pragma unroll
                for (int j = 0; j < 8; ++j) v[j] = cp[j] + rp[j];
            }
            bf16x8 bv;
            #pragma unroll
            for (int j = 0; j < 8; ++j) bv[j] = f2bf(v[j]);
            *(bf16x8*)(sAc + s * 8) = bv;
        }
        __syncthreads();
        #pragma unroll
        for (int k16l = 0; k16l < 4; ++k16l) {
            bf16x8 af = *(const bf16x8*)(sAc + ((k16l * 4 + w) * 64 + l) * 8);
            const int k16 = c * 4 + k16l;
            #pragma unroll
            for (int nt = 0; nt < 4; ++nt) {
                bf16x8 bf = *(const bf16x8*)(Bsw + ((k16 * 8 + h * 4 + nt) * 64 + l) * 8);
                acc[nt] = mfma32(af, bf, acc[nt]);
            }
        }
    }
    float* outp = (float*)(ws + (mat == 0 ? WS_LAB_CB : mat == 1 ? WS_LAB_ADD : WS_ABN_CB));
    const float* bias = mat == 0 ? b_lab : (mat == 2 ? b_abn : nullptr);
    #pragma unroll
    for (int nt = 0; nt < 4; ++nt) {
        const int col = h * 128 + nt * 32 + (l & 31);
        const float b = bias ? bias[col] : 0.f;
        #pragma unroll
        for (int reg = 0; reg < 16; ++reg) {
            const int e = w * 32 + (reg & 3) + 8 * (reg >> 2) + 4 * (l >> 5);
            outp[e * NF + col] = acc[nt][reg] + b;
        }
    }
}

// ---------------------------------------------------------------------------
// Main per-(b,t) fused kernel: 2x MFMA 64x256x256 + edge scatter + 2x MFMA
// 16x256x256 + final o2a gather. Barrier-free K-loops.
// ---------------------------------------------------------------------------
__device__ __forceinline__ void stage_A(const float* __restrict__ X, short* __restrict__ sA, int tid) {
    #pragma unroll
    for (int ss = 0; ss < 8; ++ss) {
        const int s = tid + 256 * ss;
        const int k16 = s >> 7, rt = (s >> 6) & 1, l = s & 63;
        const int row = rt * 32 + (l & 31);
        const int kb = k16 * 16 + ((l >> 5) & 1) * 8;
        const float* xp = X + row * NF + kb;
        float4 x0 = *(const float4*)xp;
        float4 x1 = *(const float4*)(xp + 4);
        bf16x8 v;
        v[0] = f2bf(x0.x); v[1] = f2bf(x0.y); v[2] = f2bf(x0.z); v[3] = f2bf(x0.w);
        v[4] = f2bf(x1.x); v[5] = f2bf(x1.y); v[6] = f2bf(x1.z); v[7] = f2bf(x1.w);
        *(bf16x8*)(sA + s * 8) = v;
    }
}

template <bool HASADD>
__device__ __forceinline__ void gemm_big(
    const short* __restrict__ sA, const short* __restrict__ Bsw,
    const float* __restrict__ cb, const float* __restrict__ addt,
    const float* __restrict__ invD,
    const int* __restrict__ rs, const int* __restrict__ re, const int* __restrict__ ro,
    float* __restrict__ sAcc, int tid) {
    const int l = tid & 63, w = tid >> 6;
    f32x16 acc[2][2];
    #pragma unroll
    for (int i = 0; i < 2; ++i)
        #pragma unroll
        for (int j = 0; j < 2; ++j)
            #pragma unroll
            for (int r = 0; r < 16; ++r) acc[i][j][r] = 0.f;

    #pragma unroll 4
    for (int k16 = 0; k16 < 16; ++k16) {
        bf16x8 a0 = *(const bf16x8*)(sA + ((k16 * 2 + 0) * 64 + l) * 8);
        bf16x8 a1 = *(const bf16x8*)(sA + ((k16 * 2 + 1) * 64 + l) * 8);
        bf16x8 b0 = *(const bf16x8*)(Bsw + ((k16 * 8 + 2 * w + 0) * 64 + l) * 8);
        bf16x8 b1 = *(const bf16x8*)(Bsw + ((k16 * 8 + 2 * w + 1) * 64 + l) * 8);
        acc[0][0] = mfma32(a0, b0, acc[0][0]);
        acc[0][1] = mfma32(a0, b1, acc[0][1]);
        acc[1][0] = mfma32(a1, b0, acc[1][0]);
        acc[1][1] = mfma32(a1, b1, acc[1][1]);
    }

    // fused edge-scatter epilogue (cb already includes bias)
    #pragma unroll
    for (int rt = 0; rt < 2; ++rt)
        #pragma unroll
        for (int nt = 0; nt < 2; ++nt) {
            const int col = w * 64 + nt * 32 + (l & 31);
            #pragma unroll
            for (int reg = 0; reg < 16; ++reg) {
                const int r = rt * 32 + (reg & 3) + 8 * (reg >> 2) + 4 * (l >> 5);
                const float v0 = acc[rt][nt][reg];
                const int s0 = rs[r], s1 = rs[r + 1];
                for (int ii = s0; ii < s1; ++ii) {
                    const int e = re[ii], o = ro[ii];
                    float v = tanh_fast(v0 + cb[e * NF + col]);
                    if (HASADD) v += addt[e * NF + col];
                    atomicAdd(&sAcc[o * SLD + col], v * invD[o]);
                }
            }
        }
}

template <int POST>   // 0: tanh * mask ; 1: plain + bias
__device__ __forceinline__ void gemm_small(
    const float* __restrict__ sIn, const short* __restrict__ Bsw,
    const float* __restrict__ bias, const float* __restrict__ mask,
    float* __restrict__ sOut, int tid) {
    const int l = tid & 63, w = tid >> 6;
    f32x4 acc[4];
    #pragma unroll
    for (int i = 0; i < 4; ++i) { acc[i][0] = 0.f; acc[i][1] = 0.f; acc[i][2] = 0.f; acc[i][3] = 0.f; }
    #pragma unroll 2
    for (int k32 = 0; k32 < 8; ++k32) {
        const float* ap = sIn + (l & 15) * SLD + k32 * 32 + ((l >> 4) & 3) * 8;
        bf16x8 af;
        #pragma unroll
        for (int j = 0; j < 8; ++j) af[j] = f2bf(ap[j]);
        #pragma unroll
        for (int nt = 0; nt < 4; ++nt) {
            bf16x8 bf = *(const bf16x8*)(Bsw + ((k32 * 16 + w * 4 + nt) * 64 + l) * 8);
            acc[nt] = mfma16(af, bf, acc[nt]);
        }
    }
    #pragma unroll
    for (int nt = 0; nt < 4; ++nt) {
        const int col = w * 64 + nt * 16 + (l & 15);
        const float b = bias[col];
        #pragma unroll
        for (int reg = 0; reg < 4; ++reg) {
            const int row = ((l >> 4) & 3) * 4 + reg;
            float v = acc[nt][reg] + b;
            if (POST == 0) v = tanh_fast(v) * mask[row];
            sOut[row * SLD + col] = v;
        }
    }
}

__global__ __launch_bounds__(256, 2) void kg_main(
    const float* __restrict__ lab_feats, const float* __restrict__ abn_feats,
    const float* __restrict__ b_org, const float* __restrict__ b_o2a,
    const char* __restrict__ ws, float* __restrict__ out) {
    // LDS: 32 KB A-frags (reused as states/msg) + 16.6 KB organ acc = 49.4 KB
    __shared__ __align__(16) char lds[32768 + NORG * SLD * 4];
    short* sA   = (short*)lds;
    float* sSt  = (float*)lds;                       // after gemms
    float* sMsg = (float*)(lds + NORG * SLD * 4);    // 16640..33280 (inside 32K)
    float* sAcc = (float*)(lds + 32768);

    const int tid = threadIdx.x;
    const int bt = blockIdx.x;

    const short* swLab1 = (const short*)(ws + WS_SW_LAB1);
    const short* swAbn1 = (const short*)(ws + WS_SW_ABN1);
    const short* swOrg  = (const short*)(ws + WS_SW_ORG);
    const short* swO2a  = (const short*)(ws + WS_SW_O2A);
    const float* lab_cb  = (const float*)(ws + WS_LAB_CB);
    const float* lab_add = (const float*)(ws + WS_LAB_ADD);
    const float* abn_cb  = (const float*)(ws + WS_ABN_CB);
    const float* wcnt = (const float*)(ws + WS_WCNT);
    const float* invL = (const float*)(ws + WS_INVL);
    const float* invA = (const float*)(ws + WS_INVA);
    const float* mskF = (const float*)(ws + WS_MASK);
    const int* lrs = (const int*)(ws + WS_LRS);
    const int* lre = (const int*)(ws + WS_LRE);
    const int* lro = (const int*)(ws + WS_LRO);
    const int* ars = (const int*)(ws + WS_ARS);
    const int* are = (const int*)(ws + WS_ARE);
    const int* aro = (const int*)(ws + WS_ARO);

    for (int i = tid; i < NORG * SLD; i += 256) sAcc[i] = 0.f;

    // ---- lab GEMM + scatter ----
    stage_A(lab_feats + bt * (NROW * NF), sA, tid);
    __syncthreads();
    gemm_big<true>(sA, swLab1, lab_cb, lab_add, invL, lrs, lre, lro, sAcc, tid);
    __syncthreads();   // all reads of sA + atomics done

    // ---- abn GEMM + scatter ----
    stage_A(abn_feats + bt * (NROW * NF), sA, tid);
    __syncthreads();
    gemm_big<false>(sA, swAbn1, abn_cb, nullptr, invA, ars, are, aro, sAcc, tid);
    __syncthreads();

    // ---- organ_states = tanh(m @ W_org + b_org) * mask ----
    gemm_small<0>(sAcc, swOrg, b_org, mskF, sSt, tid);
    __syncthreads();
    // ---- msg = states @ W_o2a + b_o2a ----
    gemm_small<1>(sSt, swO2a, b_o2a, nullptr, sMsg, tid);
    __syncthreads();

    // ---- out[a][g] = abn_feats + sum_o wcnt[a][o] * msg[o][g] ----
    {
        const int g4 = tid & 63, ah = tid >> 6;
        const float4* src4 = (const float4*)(abn_feats + bt * (NROW * NF));
        float4* dst4 = (float4*)(out + bt * (NROW * NF));
        for (int t = 0; t < 16; ++t) {
            const int a = ah * 16 + t;
            const float* wr = wcnt + a * NORG;
            float4 s = src4[a * 64 + g4];
            #pragma unroll
            for (int o = 0; o < NORG; ++o) {
                const float wv = wr[o];
                const float* m = sMsg + o * SLD + g4 * 4;
                s.x += wv * m[0]; s.y += wv * m[1]; s.z += wv * m[2]; s.w += wv * m[3];
            }
            dst4[a * 64 + g4] = s;
        }
    }
}

// ---------------------------------------------------------------------------
extern "C" void kernel_launch(void* const* d_in, const int* in_sizes, int n_in,
                              void* d_out, int out_size, void* d_ws, size_t ws_size,
                              hipStream_t stream) {
    const float* lab_feats   = (const float*)d_in[0];
    const float* abn_feats   = (const float*)d_in[1];
    const float* lab_concept = (const float*)d_in[2];
    const float* abn_concept = (const float*)d_in[3];
    const float* lab_rel     = (const float*)d_in[4];
    const float* abn_rel     = (const float*)d_in[5];
    const float* W_lab       = (const float*)d_in[6];
    const float* b_lab       = (const float*)d_in[7];
    const float* W_abn       = (const float*)d_in[8];
    const float* b_abn       = (const float*)d_in[9];
    const float* W_org       = (const float*)d_in[10];
    const float* b_org       = (const float*)d_in[11];
    const float* D           = (const float*)d_in[12];
    const float* W_o2a       = (const float*)d_in[13];
    const float* b_o2a       = (const float*)d_in[14];
    const int* lab_idx     = (const int*)d_in[16];
    const int* lab_org_idx = (const int*)d_in[17];
    const int* abn_idx     = (const int*)d_in[18];
    const int* abn_org_idx = (const int*)d_in[19];
    const int* o2a_abn_idx = (const int*)d_in[20];
    const int* o2a_org_idx = (const int*)d_in[21];
    char* ws = (char*)d_ws;
    float* out = (float*)d_out;

    pk_swz<<<416, 256, 0, stream>>>(W_lab, W_abn, D, W_org, W_o2a, ws);
    pk_meta<<<1, 128, 0, stream>>>(lab_idx, lab_org_idx, abn_idx, abn_org_idx,
                                   o2a_abn_idx, o2a_org_idx, ws);
    pk_bias2<<<6, 256, 0, stream>>>(lab_concept, abn_concept, lab_rel, abn_rel,
                                    b_lab, b_abn, lab_idx, abn_idx, ws);
    kg_main<<<NBT, 256, 0, stream>>>(lab_feats, abn_feats, b_org, b_o2a, ws, out);
}

// Round 3
// 377.907 us; speedup vs baseline: 1.4551x; 1.0428x over previous
//
#include <hip/hip_runtime.h>
#include <math.h>

// Problem constants
#define NBT   512      // B*T
#define NF    256      // FL = FA = FO
#define NC    768      // C
#define NROW  64       // L = A
#define NORG  16       // O
#define NE    128      // EL = EA = EO
#define SLD   260      // padded fp32 row stride for 16-row LDS tiles

// ---- ws byte offsets -------------------------------------------------------
#define WS_SW_LAB1  0         // 256x256 bf16, 32-style frag order
#define WS_SW_ABN1  131072    // 256x256
#define WS_SW_LAB2  262144    // 768x256
#define WS_SW_D     655360    // 768x256
#define WS_SW_ABN2  1048576   // 768x256
#define WS_SW_ORG   1441792   // 256x256, 16-style
#define WS_SW_O2A   1572864   // 256x256, 16-style
#define WS_LAB_CB   1703936   // 128x256 f32 (bias folded)
#define WS_LAB_ADD  1835008
#define WS_ABN_CB   1966080
#define WS_WCNT     2097152   // 64x16 f32
#define WS_INVL     2101248   // 16 f32
#define WS_INVA     2101312
#define WS_MASK     2101376

typedef __attribute__((ext_vector_type(8)))  short bf16x8;
typedef __attribute__((ext_vector_type(16))) float f32x16;
typedef __attribute__((ext_vector_type(4)))  float f32x4;

__device__ __forceinline__ short f2bf(float f) {
    union { float f; unsigned u; } v; v.f = f;
    unsigned r = v.u + 0x7FFF + ((v.u >> 16) & 1);   // RNE
    return (short)(r >> 16);
}
__device__ __forceinline__ float tanh_fast(float x) {
    float xc = fminf(fmaxf(x, -15.f), 15.f);
    float e = __expf(2.f * xc);
    return 1.f - 2.f / (e + 1.f);
}
__device__ __forceinline__ f32x16 mfma32(bf16x8 a, bf16x8 b, f32x16 c) {
    return __builtin_amdgcn_mfma_f32_32x32x16_bf16(a, b, c, 0, 0, 0);
}
__device__ __forceinline__ f32x4 mfma16(bf16x8 a, bf16x8 b, f32x4 c) {
    return __builtin_amdgcn_mfma_f32_16x16x32_bf16(a, b, c, 0, 0, 0);
}
// pack 8 consecutive fp32 -> bf16x8 (truncation) using v_perm_b32 (1 op / 2 elems)
__device__ __forceinline__ bf16x8 load_a16(const float* __restrict__ p) {
    float4 x0 = *(const float4*)p;
    float4 x1 = *(const float4*)(p + 4);
    union { bf16x8 v; unsigned u[4]; } r;
    r.u[0] = __builtin_amdgcn_perm(__float_as_uint(x0.y), __float_as_uint(x0.x), 0x07060302);
    r.u[1] = __builtin_amdgcn_perm(__float_as_uint(x0.w), __float_as_uint(x0.z), 0x07060302);
    r.u[2] = __builtin_amdgcn_perm(__float_as_uint(x1.y), __float_as_uint(x1.x), 0x07060302);
    r.u[3] = __builtin_amdgcn_perm(__float_as_uint(x1.w), __float_as_uint(x1.z), 0x07060302);
    return r.v;
}

// ---------------------------------------------------------------------------
// PK0: swizzle weights to bf16 fragment-order tables in ws.
// 32-style: slot s -> l=s&63, nt=(s>>6)&7, k16=s>>9; n=nt*32+(l&31), k=k16*16+((l>>5)&1)*8+j
// 16-style: l=s&63, nt=(s>>6)&15, k32=s>>10; n=nt*16+(l&15), k=k32*32+((l>>4)&3)*8+j
// ---------------------------------------------------------------------------
__device__ __forceinline__ void swz32(const float* __restrict__ src, short* __restrict__ dst, int s) {
    const int l = s & 63, rest = s >> 6;
    const int nt = rest & 7, k16 = rest >> 3;
    const int n = nt * 32 + (l & 31);
    const int kb = k16 * 16 + ((l >> 5) & 1) * 8;
    bf16x8 v;
    #pragma unroll
    for (int j = 0; j < 8; ++j) v[j] = f2bf(src[(kb + j) * NF + n]);
    *(bf16x8*)(dst + s * 8) = v;
}
__device__ __forceinline__ void swz16(const float* __restrict__ src, short* __restrict__ dst, int s) {
    const int l = s & 63, rest = s >> 6;
    const int nt = rest & 15, k32 = rest >> 4;
    const int n = nt * 16 + (l & 15);
    const int kb = k32 * 32 + ((l >> 4) & 3) * 8;
    bf16x8 v;
    #pragma unroll
    for (int j = 0; j < 8; ++j) v[j] = f2bf(src[(kb + j) * NF + n]);
    *(bf16x8*)(dst + s * 8) = v;
}

__global__ __launch_bounds__(256) void pk_swz(
    const float* __restrict__ W_lab, const float* __restrict__ W_abn,
    const float* __restrict__ D, const float* __restrict__ W_org,
    const float* __restrict__ W_o2a, char* __restrict__ ws) {
    const int gid = blockIdx.x * 256 + threadIdx.x;
    if      (gid <  8192) swz32(W_lab,            (short*)(ws + WS_SW_LAB1), gid);
    else if (gid < 16384) swz32(W_abn,            (short*)(ws + WS_SW_ABN1), gid - 8192);
    else if (gid < 40960) swz32(W_lab + NF * NF,  (short*)(ws + WS_SW_LAB2), gid - 16384);
    else if (gid < 65536) swz32(D,                (short*)(ws + WS_SW_D),    gid - 40960);
    else if (gid < 90112) swz32(W_abn + NF * NF,  (short*)(ws + WS_SW_ABN2), gid - 65536);
    else if (gid < 98304) swz16(W_org,            (short*)(ws + WS_SW_ORG),  gid - 90112);
    else                  swz16(W_o2a,            (short*)(ws + WS_SW_O2A),  gid - 98304);
}

// ---------------------------------------------------------------------------
// PK1: metadata — per-organ degrees (invL/invA/mask) and o2a weights.
// ---------------------------------------------------------------------------
__global__ void pk_meta(const int* __restrict__ lab_org_idx, const int* __restrict__ abn_org_idx,
                        const int* __restrict__ o2a_abn_idx, const int* __restrict__ o2a_org_idx,
                        char* __restrict__ ws) {
    __shared__ int cL[NORG], cA[NORG], cC[NROW * NORG];
    const int t = threadIdx.x;   // block = 128 threads
    for (int i = t; i < NROW * NORG; i += 128) cC[i] = 0;
    if (t < NORG) { cL[t] = 0; cA[t] = 0; }
    __syncthreads();
    atomicAdd(&cL[lab_org_idx[t]], 1);
    atomicAdd(&cA[abn_org_idx[t]], 1);
    atomicAdd(&cC[o2a_abn_idx[t] * NORG + o2a_org_idx[t]], 1);
    __syncthreads();
    float* invL = (float*)(ws + WS_INVL);
    float* invA = (float*)(ws + WS_INVA);
    float* mskF = (float*)(ws + WS_MASK);
    if (t < NORG) {
        invL[t] = cL[t] > 0 ? 1.0f / (float)cL[t] : 0.0f;
        invA[t] = cA[t] > 0 ? 1.0f / (float)cA[t] : 0.0f;
        mskF[t] = (cL[t] > 0 || cA[t] > 0) ? 1.0f : 0.0f;
    }
    float* wcnt = (float*)(ws + WS_WCNT);
    if (t < NROW) {
        int dega = 0;
        for (int o = 0; o < NORG; ++o) dega += cC[t * NORG + o];
        float inv = 1.0f / (float)(dega > 1 ? dega : 1);
        for (int o = 0; o < NORG; ++o) wcnt[t * NORG + o] = (float)cC[t * NORG + o] * inv;
    }
}

// ---------------------------------------------------------------------------
// PK2: per-edge bias tables via MFMA. grid = 24: mat(3) x col-half(2) x edge-quarter(4).
// Each block: M=32 edges, N=128 cols, K=768. No atomics.
// ---------------------------------------------------------------------------
__global__ __launch_bounds__(256) void pk_bias2(
    const float* __restrict__ lab_con, const float* __restrict__ abn_con,
    const float* __restrict__ lab_rel, const float* __restrict__ abn_rel,
    const float* __restrict__ b_lab, const float* __restrict__ b_abn,
    const int* __restrict__ lab_idx, const int* __restrict__ abn_idx,
    char* __restrict__ ws) {
    __shared__ __align__(16) short sAc[256 * 8];   // 4 KB A k-chunk (32 edges x 64 k)
    const int tid = threadIdx.x, l = tid & 63, w = tid >> 6;
    const int mat = blockIdx.x >> 3, h = (blockIdx.x >> 2) & 1, mq = blockIdx.x & 3;
    const int em = mq * 32;
    const int ntg = h * 4 + w;
    const short* Bsw = (const short*)(ws + (mat == 0 ? WS_SW_LAB2 : mat == 1 ? WS_SW_D : WS_SW_ABN2));
    const int eL = tid >> 3, kq = tid & 7;   // staging: octet-per-edge (coalesced)
    f32x16 acc;
    #pragma unroll
    for (int r = 0; r < 16; ++r) acc[r] = 0.f;

    for (int c = 0; c < 12; ++c) {           // K chunks of 64
        __syncthreads();
        {
            const int e = em + eL;
            const int k = c * 64 + kq * 8;
            float v[8];
            if (mat == 1) {
                const float* rp = lab_rel + e * NC + k;
                float4 r0 = *(const float4*)rp, r1 = *(const float4*)(rp + 4);
                v[0]=r0.x; v[1]=r0.y; v[2]=r0.z; v[3]=r0.w; v[4]=r1.x; v[5]=r1.y; v[6]=r1.z; v[7]=r1.w;
            } else {
                const float* cp = (mat == 0 ? lab_con + lab_idx[e] * NC : abn_con + abn_idx[e] * NC) + k;
                const float* rp = (mat == 0 ? lab_rel : abn_rel) + e * NC + k;
                float4 c0 = *(const float4*)cp, c1 = *(const float4*)(cp + 4);
                float4 r0 = *(const float4*)rp, r1 = *(const float4*)(rp + 4);
                v[0]=c0.x+r0.x; v[1]=c0.y+r0.y; v[2]=c0.z+r0.z; v[3]=c0.w+r0.w;
                v[4]=c1.x+r1.x; v[5]=c1.y+r1.y; v[6]=c1.z+r1.z; v[7]=c1.w+r1.w;
            }
            bf16x8 bv;
            #pragma unroll
            for (int j = 0; j < 8; ++j) bv[j] = f2bf(v[j]);
            const int slot = (kq >> 1) * 64 + (kq & 1) * 32 + eL;
            *(bf16x8*)(sAc + slot * 8) = bv;
        }
        __syncthreads();
        #pragma unroll
        for (int k16l = 0; k16l < 4; ++k16l) {
            bf16x8 af = *(const bf16x8*)(sAc + (k16l * 64 + l) * 8);
            bf16x8 bfv = *(const bf16x8*)(Bsw + (((c * 4 + k16l) * 8 + ntg) * 64 + l) * 8);
            acc = mfma32(af, bfv, acc);
        }
    }
    float* outp = (float*)(ws + (mat == 0 ? WS_LAB_CB : mat == 1 ? WS_LAB_ADD : WS_ABN_CB));
    const float* bias = mat == 0 ? b_lab : (mat == 2 ? b_abn : nullptr);
    const int col = ntg * 32 + (l & 31);
    const float b = bias ? bias[col] : 0.f;
    #pragma unroll
    for (int reg = 0; reg < 16; ++reg) {
        const int e = em + (reg & 3) + 8 * (reg >> 2) + 4 * (l >> 5);
        outp[e * NF + col] = acc[reg] + b;
    }
}

// ---------------------------------------------------------------------------
// Main per-(b,t) kernel. Edges-as-rows MFMA GEMMs (M=128,N=256,K=256), A-frags
// straight from global (row-gather through idx), uniform scatter epilogue.
// ---------------------------------------------------------------------------
template <bool HASADD>
__device__ __forceinline__ void gemm_big(
    const float* __restrict__ X,              // 64x256 fp32 (this bt)
    const int*  __restrict__ ridx,            // 128 edge -> row
    const short* __restrict__ Bsw,
    const float* __restrict__ cb, const float* __restrict__ addt,
    const int* __restrict__ sOrg, const float* __restrict__ sScl, int ebase,
    float* __restrict__ sAcc, int tid) {
    const int l = tid & 63, w = tid >> 6;
    const float* px[4];
    #pragma unroll
    for (int rt = 0; rt < 4; ++rt) {
        const int e = rt * 32 + (l & 31);
        px[rt] = X + ridx[e] * NF + (l >> 5) * 8;
    }
    f32x16 acc[4][2];
    #pragma unroll
    for (int i = 0; i < 4; ++i)
        #pragma unroll
        for (int j = 0; j < 2; ++j)
            #pragma unroll
            for (int r = 0; r < 16; ++r) acc[i][j][r] = 0.f;

    #pragma unroll 2
    for (int k16 = 0; k16 < 16; ++k16) {
        bf16x8 a[4];
        #pragma unroll
        for (int rt = 0; rt < 4; ++rt) a[rt] = load_a16(px[rt] + k16 * 16);
        bf16x8 b0 = *(const bf16x8*)(Bsw + ((k16 * 8 + 2 * w + 0) * 64 + l) * 8);
        bf16x8 b1 = *(const bf16x8*)(Bsw + ((k16 * 8 + 2 * w + 1) * 64 + l) * 8);
        #pragma unroll
        for (int rt = 0; rt < 4; ++rt) {
            acc[rt][0] = mfma32(a[rt], b0, acc[rt][0]);
            acc[rt][1] = mfma32(a[rt], b1, acc[rt][1]);
        }
    }

    // uniform epilogue: one known edge per acc element
    #pragma unroll
    for (int rt = 0; rt < 4; ++rt) {
        #pragma unroll
        for (int reg = 0; reg < 16; ++reg) {
            const int e = rt * 32 + (reg & 3) + 8 * (reg >> 2) + 4 * (l >> 5);
            const int o = sOrg[ebase + e];
            const float sc = sScl[ebase + e];
            #pragma unroll
            for (int nt = 0; nt < 2; ++nt) {
                const int col = w * 64 + nt * 32 + (l & 31);
                float v = tanh_fast(acc[rt][nt][reg] + cb[e * NF + col]);
                if (HASADD) v += addt[e * NF + col];
                atomicAdd(&sAcc[o * SLD + col], v * sc);
            }
        }
    }
}

template <int POST>   // 0: tanh * mask ; 1: plain
__device__ __forceinline__ void gemm_small(
    const float* __restrict__ sIn, const short* __restrict__ Bsw,
    const float* __restrict__ bias, const float* __restrict__ mask,
    float* __restrict__ sOut, int tid) {
    const int l = tid & 63, w = tid >> 6;
    f32x4 acc[4];
    #pragma unroll
    for (int i = 0; i < 4; ++i) { acc[i][0] = 0.f; acc[i][1] = 0.f; acc[i][2] = 0.f; acc[i][3] = 0.f; }
    #pragma unroll 2
    for (int k32 = 0; k32 < 8; ++k32) {
        const float* ap = sIn + (l & 15) * SLD + k32 * 32 + ((l >> 4) & 3) * 8;
        bf16x8 af = load_a16(ap);
        #pragma unroll
        for (int nt = 0; nt < 4; ++nt) {
            bf16x8 bfv = *(const bf16x8*)(Bsw + ((k32 * 16 + w * 4 + nt) * 64 + l) * 8);
            acc[nt] = mfma16(af, bfv, acc[nt]);
        }
    }
    #pragma unroll
    for (int nt = 0; nt < 4; ++nt) {
        const int col = w * 64 + nt * 16 + (l & 15);
        const float b = bias[col];
        #pragma unroll
        for (int reg = 0; reg < 4; ++reg) {
            const int row = ((l >> 4) & 3) * 4 + reg;
            float v = acc[nt][reg] + b;
            if (POST == 0) v = tanh_fast(v) * mask[row];
            sOut[row * SLD + col] = v;
        }
    }
}

__global__ __launch_bounds__(256, 2) void kg_main(
    const float* __restrict__ lab_feats, const float* __restrict__ abn_feats,
    const int* __restrict__ lab_idx, const int* __restrict__ abn_idx,
    const int* __restrict__ lab_org_idx, const int* __restrict__ abn_org_idx,
    const float* __restrict__ b_org, const float* __restrict__ b_o2a,
    const char* __restrict__ ws, float* __restrict__ out) {
    __shared__ __align__(16) float sAcc[NORG * SLD];   // organ accumulator
    __shared__ __align__(16) float sSt [NORG * SLD];   // organ states
    __shared__ __align__(16) float sMsg[NORG * SLD];   // messages
    __shared__ int   sOrg[2 * NE];
    __shared__ float sScl[2 * NE];

    const int tid = threadIdx.x;
    const int bt = blockIdx.x;

    const short* swLab1 = (const short*)(ws + WS_SW_LAB1);
    const short* swAbn1 = (const short*)(ws + WS_SW_ABN1);
    const short* swOrg  = (const short*)(ws + WS_SW_ORG);
    const short* swO2a  = (const short*)(ws + WS_SW_O2A);
    const float* lab_cb  = (const float*)(ws + WS_LAB_CB);
    const float* lab_add = (const float*)(ws + WS_LAB_ADD);
    const float* abn_cb  = (const float*)(ws + WS_ABN_CB);
    const float* invL = (const float*)(ws + WS_INVL);
    const float* invA = (const float*)(ws + WS_INVA);
    const float* mskF = (const float*)(ws + WS_MASK);

    for (int i = tid; i < NORG * SLD; i += 256) sAcc[i] = 0.f;
    if (tid < NE) { const int o = lab_org_idx[tid]; sOrg[tid] = o; sScl[tid] = invL[o]; }
    else          { const int o = abn_org_idx[tid - NE]; sOrg[tid] = o; sScl[tid] = invA[o]; }
    __syncthreads();

    const float* Xl = lab_feats + bt * (NROW * NF);
    const float* Xa = abn_feats + bt * (NROW * NF);
    gemm_big<true >(Xl, lab_idx, swLab1, lab_cb, lab_add, sOrg, sScl, 0,  sAcc, tid);
    gemm_big<false>(Xa, abn_idx, swAbn1, abn_cb, nullptr,  sOrg, sScl, NE, sAcc, tid);
    __syncthreads();   // all scatter atomics visible

    gemm_small<0>(sAcc, swOrg, b_org, mskF, sSt, tid);
    __syncthreads();
    gemm_small<1>(sSt, swO2a, b_o2a, nullptr, sMsg, tid);
    __syncthreads();

    // out[a][g] = abn_feats[a][g] + sum_o wcnt[a][o]*msg[o][g]; wcnt via scalar loads
    {
        const int g = tid;
        float mr[NORG];
        #pragma unroll
        for (int o = 0; o < NORG; ++o) mr[o] = sMsg[o * SLD + g];
        const float* src = abn_feats + bt * (NROW * NF);
        float* dst = out + bt * (NROW * NF);
        const float* wc = (const float*)(ws + WS_WCNT);
        #pragma unroll 4
        for (int a = 0; a < NROW; ++a) {
            float s = src[a * NF + g];
            #pragma unroll
            for (int o = 0; o < NORG; ++o) s += wc[a * NORG + o] * mr[o];
            dst[a * NF + g] = s;
        }
    }
}

// ---------------------------------------------------------------------------
extern "C" void kernel_launch(void* const* d_in, const int* in_sizes, int n_in,
                              void* d_out, int out_size, void* d_ws, size_t ws_size,
                              hipStream_t stream) {
    const float* lab_feats   = (const float*)d_in[0];
    const float* abn_feats   = (const float*)d_in[1];
    const float* lab_concept = (const float*)d_in[2];
    const float* abn_concept = (const float*)d_in[3];
    const float* lab_rel     = (const float*)d_in[4];
    const float* abn_rel     = (const float*)d_in[5];
    const float* W_lab       = (const float*)d_in[6];
    const float* b_lab       = (const float*)d_in[7];
    const float* W_abn       = (const float*)d_in[8];
    const float* b_abn       = (const float*)d_in[9];
    const float* W_org       = (const float*)d_in[10];
    const float* b_org       = (const float*)d_in[11];
    const float* D           = (const float*)d_in[12];
    const float* W_o2a       = (const float*)d_in[13];
    const float* b_o2a       = (const float*)d_in[14];
    const int* lab_idx     = (const int*)d_in[16];
    const int* lab_org_idx = (const int*)d_in[17];
    const int* abn_idx     = (const int*)d_in[18];
    const int* abn_org_idx = (const int*)d_in[19];
    const int* o2a_abn_idx = (const int*)d_in[20];
    const int* o2a_org_idx = (const int*)d_in[21];
    char* ws = (char*)d_ws;
    float* out = (float*)d_out;

    pk_swz<<<416, 256, 0, stream>>>(W_lab, W_abn, D, W_org, W_o2a, ws);
    pk_meta<<<1, 128, 0, stream>>>(lab_org_idx, abn_org_idx, o2a_abn_idx, o2a_org_idx, ws);
    pk_bias2<<<24, 256, 0, stream>>>(lab_concept, abn_concept, lab_rel, abn_rel,
                                     b_lab, b_abn, lab_idx, abn_idx, ws);
    kg_main<<<NBT, 256, 0, stream>>>(lab_feats, abn_feats, lab_idx, abn_idx,
                                     lab_org_idx, abn_org_idx, b_org, b_o2a, ws, out);
}

// Round 5
// 275.848 us; speedup vs baseline: 1.9935x; 1.3700x over previous
//
#include <hip/hip_runtime.h>
#include <math.h>

// Problem constants
#define NBT 512
#define NF  256
#define NC  768
#define NROW 64
#define NORG 16
#define NE  128
#define SLD 260      // fp32 LDS row stride (16-row tiles)
#define SY  264      // bf16 LDS row stride for y (64 rows)

// ---- ws byte offsets ----
#define WS_SW_LAB1 0         // 256x256 bf16, 32-style frag order
#define WS_SW_ABN1 131072
#define WS_SW_LAB2 262144    // 768x256
#define WS_SW_D    655360    // 768x256
#define WS_SW_ABN2 1048576   // 768x256
#define WS_SW_ORG  1441792   // 256x256, 16-style
#define WS_SW_O2A  1572864
#define WS_SUMREL  1703936   // 16x768 f32 per-organ sums of lab_rel
#define WS_LAB_CB  1753088   // 128x256 f32 (bias folded)
#define WS_ABN_CB  1884160
#define WS_ADDSUM  2015232   // 16x256 f32: raw per-organ sums of rel@D
#define WS_WCNT    2031616   // 64x16 f32
#define WS_INVL    2035712
#define WS_INVA    2035776
#define WS_MASK    2035840
#define WS_SRTL    2035904   // 128 ints: (row<<24)|(org<<16)|e, organ-sorted
#define WS_SRTA    2036544

typedef __attribute__((ext_vector_type(8)))  short bf16x8;
typedef __attribute__((ext_vector_type(16))) float f32x16;
typedef __attribute__((ext_vector_type(4)))  float f32x4;

__device__ __forceinline__ short f2bf(float f) {
    union { float f; unsigned u; } v; v.f = f;
    unsigned r = v.u + 0x7FFF + ((v.u >> 16) & 1);   // RNE
    return (short)(r >> 16);
}
__device__ __forceinline__ float bf2f(short s) {
    return __uint_as_float(((unsigned)(unsigned short)s) << 16);
}
__device__ __forceinline__ float tanh_fast(float x) {
    float xc = fminf(fmaxf(x, -15.f), 15.f);
    float e = __expf(2.f * xc);
    return 1.f - 2.f / (e + 1.f);
}
__device__ __forceinline__ f32x16 mfma32(bf16x8 a, bf16x8 b, f32x16 c) {
    return __builtin_amdgcn_mfma_f32_32x32x16_bf16(a, b, c, 0, 0, 0);
}
__device__ __forceinline__ f32x4 mfma16(bf16x8 a, bf16x8 b, f32x4 c) {
    return __builtin_amdgcn_mfma_f32_16x16x32_bf16(a, b, c, 0, 0, 0);
}
__device__ __forceinline__ bf16x8 pack_a16(const float* __restrict__ p) {
    float4 x0 = *(const float4*)p;
    float4 x1 = *(const float4*)(p + 4);
    union { bf16x8 v; unsigned u[4]; } r;
    r.u[0] = __builtin_amdgcn_perm(__float_as_uint(x0.y), __float_as_uint(x0.x), 0x07060302);
    r.u[1] = __builtin_amdgcn_perm(__float_as_uint(x0.w), __float_as_uint(x0.z), 0x07060302);
    r.u[2] = __builtin_amdgcn_perm(__float_as_uint(x1.y), __float_as_uint(x1.x), 0x07060302);
    r.u[3] = __builtin_amdgcn_perm(__float_as_uint(x1.w), __float_as_uint(x1.z), 0x07060302);
    return r.v;
}

// ---------------------------------------------------------------------------
// PK0 (pk_pre): 0..415 weight swizzle, 416 metadata, 417..464 per-organ rel sums.
// ---------------------------------------------------------------------------
__device__ __forceinline__ void swz32(const float* __restrict__ src, short* __restrict__ dst, int s) {
    const int l = s & 63, rest = s >> 6;
    const int nt = rest & 7, k16 = rest >> 3;
    const int n = nt * 32 + (l & 31);
    const int kb = k16 * 16 + ((l >> 5) & 1) * 8;
    bf16x8 v;
    #pragma unroll
    for (int j = 0; j < 8; ++j) v[j] = f2bf(src[(kb + j) * NF + n]);
    *(bf16x8*)(dst + s * 8) = v;
}
__device__ __forceinline__ void swz16(const float* __restrict__ src, short* __restrict__ dst, int s) {
    const int l = s & 63, rest = s >> 6;
    const int nt = rest & 15, k32 = rest >> 4;
    const int n = nt * 16 + (l & 15);
    const int kb = k32 * 32 + ((l >> 4) & 3) * 8;
    bf16x8 v;
    #pragma unroll
    for (int j = 0; j < 8; ++j) v[j] = f2bf(src[(kb + j) * NF + n]);
    *(bf16x8*)(dst + s * 8) = v;
}

__global__ __launch_bounds__(256) void pk_pre(
    const float* __restrict__ W_lab, const float* __restrict__ W_abn,
    const float* __restrict__ D, const float* __restrict__ W_org,
    const float* __restrict__ W_o2a, const float* __restrict__ lab_rel,
    const int* __restrict__ lab_idx, const int* __restrict__ lab_org_idx,
    const int* __restrict__ abn_idx, const int* __restrict__ abn_org_idx,
    const int* __restrict__ o2a_abn_idx, const int* __restrict__ o2a_org_idx,
    char* __restrict__ ws) {
    const int bid = blockIdx.x;
    if (bid < 416) {
        const int gid = bid * 256 + threadIdx.x;
        if      (gid <  8192) swz32(W_lab,           (short*)(ws + WS_SW_LAB1), gid);
        else if (gid < 16384) swz32(W_abn,           (short*)(ws + WS_SW_ABN1), gid - 8192);
        else if (gid < 40960) swz32(W_lab + NF * NF, (short*)(ws + WS_SW_LAB2), gid - 16384);
        else if (gid < 65536) swz32(D,               (short*)(ws + WS_SW_D),    gid - 40960);
        else if (gid < 90112) swz32(W_abn + NF * NF, (short*)(ws + WS_SW_ABN2), gid - 65536);
        else if (gid < 98304) swz16(W_org,           (short*)(ws + WS_SW_ORG),  gid - 90112);
        else                  swz16(W_o2a,           (short*)(ws + WS_SW_O2A),  gid - 98304);
    } else if (bid == 416) {
        // ---- metadata: counts, organ-sorted edge lists, wcnt ----
        __shared__ int cL[NORG], cA[NORG], cC[NROW * NORG];
        __shared__ int goL[NORG + 1], goA[NORG + 1], curL[NORG], curA[NORG];
        const int t = threadIdx.x;
        for (int i = t; i < NROW * NORG; i += 256) cC[i] = 0;
        if (t < NORG) { cL[t] = 0; cA[t] = 0; }
        __syncthreads();
        if (t < NE) {
            atomicAdd(&cL[lab_org_idx[t]], 1);
            atomicAdd(&cA[abn_org_idx[t]], 1);
            atomicAdd(&cC[o2a_abn_idx[t] * NORG + o2a_org_idx[t]], 1);
        }
        __syncthreads();
        if (t == 0) { int s = 0; for (int o = 0; o < NORG; ++o) { goL[o] = s; s += cL[o]; } goL[NORG] = s; }
        if (t == 1) { int s = 0; for (int o = 0; o < NORG; ++o) { goA[o] = s; s += cA[o]; } goA[NORG] = s; }
        __syncthreads();
        if (t < NORG) { curL[t] = goL[t]; curA[t] = goA[t]; }
        __syncthreads();
        if (t < NE) {
            const int ol = lab_org_idx[t], oa = abn_org_idx[t];
            int p = atomicAdd(&curL[ol], 1);
            ((int*)(ws + WS_SRTL))[p] = (lab_idx[t] << 24) | (ol << 16) | t;
            int q = atomicAdd(&curA[oa], 1);
            ((int*)(ws + WS_SRTA))[q] = (abn_idx[t] << 24) | (oa << 16) | t;
        }
        if (t < NORG) {
            ((float*)(ws + WS_INVL))[t] = cL[t] ? 1.f / (float)cL[t] : 0.f;
            ((float*)(ws + WS_INVA))[t] = cA[t] ? 1.f / (float)cA[t] : 0.f;
            ((float*)(ws + WS_MASK))[t] = (cL[t] || cA[t]) ? 1.f : 0.f;
        }
        if (t < NROW) {
            int dega = 0;
            for (int o = 0; o < NORG; ++o) dega += cC[t * NORG + o];
            float inv = 1.f / (float)(dega > 1 ? dega : 1);
            for (int o = 0; o < NORG; ++o)
                ((float*)(ws + WS_WCNT))[t * NORG + o] = (float)cC[t * NORG + o] * inv;
        }
    } else {
        // ---- sumRel[o][k] = sum over lab edges with org==o of lab_rel[e][k] ----
        const int b2 = bid - 417;
        const int o = b2 / 3, kth = b2 % 3;
        const int k = kth * 256 + threadIdx.x;
        float s = 0.f;
        #pragma unroll 4
        for (int e = 0; e < NE; ++e) {
            const float v = lab_rel[e * NC + k];
            s += (lab_org_idx[e] == o) ? v : 0.f;
        }
        ((float*)(ws + WS_SUMREL))[o * NC + k] = s;
    }
}

// ---------------------------------------------------------------------------
// PK2: per-edge cb tables (blocks 0..15) + raw per-organ rel@D sums (16..17).
// ---------------------------------------------------------------------------
__global__ __launch_bounds__(256) void pk_bias2(
    const float* __restrict__ lab_con, const float* __restrict__ abn_con,
    const float* __restrict__ lab_rel, const float* __restrict__ abn_rel,
    const float* __restrict__ b_lab, const float* __restrict__ b_abn,
    const int* __restrict__ lab_idx, const int* __restrict__ abn_idx,
    char* __restrict__ ws) {
    __shared__ __align__(16) short sAc[256 * 8];
    const int tid = threadIdx.x, l = tid & 63, w = tid >> 6;
    const int bid = blockIdx.x;
    if (bid < 16) {
        const int side = bid >> 3;               // 0 lab, 1 abn
        const int h = (bid >> 2) & 1, mq = bid & 3;
        const int em = mq * 32, ntg = h * 4 + w;
        const short* Bsw = (const short*)(ws + (side ? WS_SW_ABN2 : WS_SW_LAB2));
        const float* con = side ? abn_con : lab_con;
        const float* rel = side ? abn_rel : lab_rel;
        const int*   idx = side ? abn_idx : lab_idx;
        const int eL = tid >> 3, kq = tid & 7;
        f32x16 acc;
        #pragma unroll
        for (int r = 0; r < 16; ++r) acc[r] = 0.f;
        for (int c = 0; c < 12; ++c) {
            __syncthreads();
            {
                const int e = em + eL;
                const int k = c * 64 + kq * 8;
                const float* cp = con + idx[e] * NC + k;
                const float* rp = rel + e * NC + k;
                float4 c0 = *(const float4*)cp, c1 = *(const float4*)(cp + 4);
                float4 r0 = *(const float4*)rp, r1 = *(const float4*)(rp + 4);
                float v[8] = {c0.x + r0.x, c0.y + r0.y, c0.z + r0.z, c0.w + r0.w,
                              c1.x + r1.x, c1.y + r1.y, c1.z + r1.z, c1.w + r1.w};
                bf16x8 bv;
                #pragma unroll
                for (int j = 0; j < 8; ++j) bv[j] = f2bf(v[j]);
                *(bf16x8*)(sAc + ((kq >> 1) * 64 + (kq & 1) * 32 + eL) * 8) = bv;
            }
            __syncthreads();
            #pragma unroll
            for (int k16l = 0; k16l < 4; ++k16l) {
                bf16x8 af  = *(const bf16x8*)(sAc + (k16l * 64 + l) * 8);
                bf16x8 bfv = *(const bf16x8*)(Bsw + (((c * 4 + k16l) * 8 + ntg) * 64 + l) * 8);
                acc = mfma32(af, bfv, acc);
            }
        }
        float* outp = (float*)(ws + (side ? WS_ABN_CB : WS_LAB_CB));
        const float* bias = side ? b_abn : b_lab;
        const int col = ntg * 32 + (l & 31);
        const float b = bias[col];
        #pragma unroll
        for (int reg = 0; reg < 16; ++reg) {
            const int e = em + (reg & 3) + 8 * (reg >> 2) + 4 * (l >> 5);
            outp[e * NF + col] = acc[reg] + b;
        }
    } else {
        // addsum: (16-row A = sumRel, padded to 32) @ D  -> WS_ADDSUM raw
        const int h = bid & 1, ntg = h * 4 + w;
        const short* Bsw = (const short*)(ws + WS_SW_D);
        const float* sr = (const float*)(ws + WS_SUMREL);
        f32x16 acc;
        #pragma unroll
        for (int r = 0; r < 16; ++r) acc[r] = 0.f;
        for (int c = 0; c < 12; ++c) {
            __syncthreads();
            {
                const int s = tid;
                const int k16l = s >> 6, ll = s & 63;
                const int row = ll & 31;
                const int kb = c * 64 + k16l * 16 + ((ll >> 5) & 1) * 8;
                bf16x8 bv;
                if (row < NORG) {
                    bv = pack_a16(sr + row * NC + kb);
                } else {
                    for (int j = 0; j < 8; ++j) bv[j] = 0;
                }
                *(bf16x8*)(sAc + s * 8) = bv;
            }
            __syncthreads();
            #pragma unroll
            for (int k16l = 0; k16l < 4; ++k16l) {
                bf16x8 af  = *(const bf16x8*)(sAc + (k16l * 64 + l) * 8);
                bf16x8 bfv = *(const bf16x8*)(Bsw + (((c * 4 + k16l) * 8 + ntg) * 64 + l) * 8);
                acc = mfma32(af, bfv, acc);
            }
        }
        float* outp = (float*)(ws + WS_ADDSUM);
        const int col = ntg * 32 + (l & 31);
        #pragma unroll
        for (int reg = 0; reg < 16; ++reg) {
            const int row = (reg & 3) + 8 * (reg >> 2) + 4 * (l >> 5);
            if (row < NORG) outp[row * NF + col] = acc[reg];
        }
    }
}

// ---------------------------------------------------------------------------
// Main per-(b,t) kernel.
// ---------------------------------------------------------------------------
__device__ __forceinline__ void stage_A(const float* __restrict__ X, short* __restrict__ sA, int tid) {
    #pragma unroll
    for (int ss = 0; ss < 8; ++ss) {
        const int s = tid + 256 * ss;
        const int k16 = s >> 7, rt = (s >> 6) & 1, l = s & 63;
        const int row = rt * 32 + (l & 31);
        const int kb = k16 * 16 + ((l >> 5) & 1) * 8;
        *(bf16x8*)(sA + s * 8) = pack_a16(X + row * NF + kb);
    }
}

template <bool LAB>
__device__ __forceinline__ void side_pass(
    const float* __restrict__ X, const short* __restrict__ Bsw,
    const float* __restrict__ cb, const float* __restrict__ addR,
    const float* __restrict__ sInv, const int* __restrict__ sE,
    short* __restrict__ sA, float* __restrict__ sAcc, int tid) {
    __syncthreads();                 // prior users of region done
    stage_A(X, sA, tid);
    __syncthreads();
    const int l = tid & 63, w = tid >> 6;
    f32x16 acc[2][2];
    #pragma unroll
    for (int i = 0; i < 2; ++i)
        #pragma unroll
        for (int j = 0; j < 2; ++j)
            #pragma unroll
            for (int r = 0; r < 16; ++r) acc[i][j][r] = 0.f;
    #pragma unroll 8
    for (int k16 = 0; k16 < 16; ++k16) {
        bf16x8 a0 = *(const bf16x8*)(sA + ((k16 * 2 + 0) * 64 + l) * 8);
        bf16x8 a1 = *(const bf16x8*)(sA + ((k16 * 2 + 1) * 64 + l) * 8);
        bf16x8 b0 = *(const bf16x8*)(Bsw + ((k16 * 8 + 2 * w + 0) * 64 + l) * 8);
        bf16x8 b1 = *(const bf16x8*)(Bsw + ((k16 * 8 + 2 * w + 1) * 64 + l) * 8);
        acc[0][0] = mfma32(a0, b0, acc[0][0]);
        acc[1][0] = mfma32(a1, b0, acc[1][0]);
        acc[0][1] = mfma32(a0, b1, acc[0][1]);
        acc[1][1] = mfma32(a1, b1, acc[1][1]);
    }
    __syncthreads();                 // all sA reads done; region becomes sY
    short* sYs = sA;
    #pragma unroll
    for (int rt = 0; rt < 2; ++rt)
        #pragma unroll
        for (int nt = 0; nt < 2; ++nt) {
            const int col = w * 64 + nt * 32 + (l & 31);
            #pragma unroll
            for (int reg = 0; reg < 16; ++reg) {
                const int row = rt * 32 + (reg & 3) + 8 * (reg >> 2) + 4 * (l >> 5);
                sYs[row * SY + col] = f2bf(acc[rt][nt][reg]);
            }
        }
    __syncthreads();
    // per-column edge reduction; organ-sorted edges -> register accumulate
    const int t = tid;
    if (LAB) {
        #pragma unroll
        for (int o = 0; o < NORG; ++o)
            sAcc[o * SLD + t] = addR[o * NF + t] * sInv[o];
    }
    float racc = 0.f;
    int curo = (sE[0] >> 16) & 255;
    #pragma unroll 4
    for (int i = 0; i < NE; ++i) {
        const int pk = sE[i];
        const int o = (pk >> 16) & 255;
        if (o != curo) {             // wave-uniform branch
            sAcc[curo * SLD + t] += racc * sInv[curo];
            racc = 0.f; curo = o;
        }
        const float yv = bf2f(sYs[(pk >> 24) * SY + t]);
        racc += tanh_fast(yv + cb[(pk & 0xffff) * NF + t]);
    }
    sAcc[curo * SLD + t] += racc * sInv[curo];
}

template <int POST>   // 0: tanh * mask ; 1: plain
__device__ __forceinline__ void gemm_small(
    const float* __restrict__ sIn, const short* __restrict__ Bsw,
    const float* __restrict__ bias, const float* __restrict__ mask,
    float* __restrict__ sOut, int tid) {
    const int l = tid & 63, w = tid >> 6;
    f32x4 acc[4];
    #pragma unroll
    for (int i = 0; i < 4; ++i) { acc[i][0] = 0.f; acc[i][1] = 0.f; acc[i][2] = 0.f; acc[i][3] = 0.f; }
    #pragma unroll 2
    for (int k32 = 0; k32 < 8; ++k32) {
        const float* ap = sIn + (l & 15) * SLD + k32 * 32 + ((l >> 4) & 3) * 8;
        bf16x8 af = pack_a16(ap);
        #pragma unroll
        for (int nt = 0; nt < 4; ++nt) {
            bf16x8 bfv = *(const bf16x8*)(Bsw + ((k32 * 16 + w * 4 + nt) * 64 + l) * 8);
            acc[nt] = mfma16(af, bfv, acc[nt]);
        }
    }
    #pragma unroll
    for (int nt = 0; nt < 4; ++nt) {
        const int col = w * 64 + nt * 16 + (l & 15);
        const float b = bias[col];
        #pragma unroll
        for (int reg = 0; reg < 4; ++reg) {
            const int row = ((l >> 4) & 3) * 4 + reg;
            float v = acc[nt][reg] + b;
            if (POST == 0) v = tanh_fast(v) * mask[row];
            sOut[row * SLD + col] = v;
        }
    }
}

__global__ __launch_bounds__(256, 2) void kg_main(
    const float* __restrict__ lab_feats, const float* __restrict__ abn_feats,
    const float* __restrict__ b_org, const float* __restrict__ b_o2a,
    const char* __restrict__ ws, float* __restrict__ out) {
    __shared__ __align__(16) short sY[NROW * SY];        // 33792 B; aliases A-frags
    __shared__ __align__(16) float sAcc[NORG * SLD];     // 16640 B; later sMsg
    __shared__ __align__(16) float sSt [NORG * SLD];     // 16640 B
    __shared__ int   sEL[NE], sEA[NE];
    __shared__ float sInvL[NORG], sInvA[NORG], sMsk[NORG];

    const int tid = threadIdx.x;
    const int bt = blockIdx.x;

    if (tid < NE) {
        sEL[tid] = ((const int*)(ws + WS_SRTL))[tid];
        sEA[tid] = ((const int*)(ws + WS_SRTA))[tid];
    } else {
        const int u = tid - NE;
        if      (u < 16) sInvL[u]      = ((const float*)(ws + WS_INVL))[u];
        else if (u < 32) sInvA[u - 16] = ((const float*)(ws + WS_INVA))[u - 16];
        else if (u < 48) sMsk[u - 32]  = ((const float*)(ws + WS_MASK))[u - 32];
    }

    const float* Xl = lab_feats + bt * (NROW * NF);
    const float* Xa = abn_feats + bt * (NROW * NF);
    side_pass<true >(Xl, (const short*)(ws + WS_SW_LAB1),
                     (const float*)(ws + WS_LAB_CB), (const float*)(ws + WS_ADDSUM),
                     sInvL, sEL, sY, sAcc, tid);
    side_pass<false>(Xa, (const short*)(ws + WS_SW_ABN1),
                     (const float*)(ws + WS_ABN_CB), nullptr,
                     sInvA, sEA, sY, sAcc, tid);
    __syncthreads();

    gemm_small<0>(sAcc, (const short*)(ws + WS_SW_ORG), b_org, sMsk, sSt, tid);
    __syncthreads();
    float* sMsg = sAcc;   // alias (input of <1> is sSt)
    gemm_small<1>(sSt, (const short*)(ws + WS_SW_O2A), b_o2a, nullptr, sMsg, tid);
    __syncthreads();

    // out[a][g] = abn_feats[a][g] + sum_o wcnt[a][o]*msg[o][g]
    {
        const int g = tid;
        float mr[NORG];
        #pragma unroll
        for (int o = 0; o < NORG; ++o) mr[o] = sMsg[o * SLD + g];
        const float* src = abn_feats + bt * (NROW * NF);
        float* dst = out + bt * (NROW * NF);
        const float* wc = (const float*)(ws + WS_WCNT);
        #pragma unroll 4
        for (int a = 0; a < NROW; ++a) {
            float s = src[a * NF + g];
            #pragma unroll
            for (int o = 0; o < NORG; ++o) s += wc[a * NORG + o] * mr[o];
            dst[a * NF + g] = s;
        }
    }
}

// ---------------------------------------------------------------------------
extern "C" void kernel_launch(void* const* d_in, const int* in_sizes, int n_in,
                              void* d_out, int out_size, void* d_ws, size_t ws_size,
                              hipStream_t stream) {
    const float* lab_feats   = (const float*)d_in[0];
    const float* abn_feats   = (const float*)d_in[1];
    const float* lab_concept = (const float*)d_in[2];
    const float* abn_concept = (const float*)d_in[3];
    const float* lab_rel     = (const float*)d_in[4];
    const float* abn_rel     = (const float*)d_in[5];
    const float* W_lab       = (const float*)d_in[6];
    const float* b_lab       = (const float*)d_in[7];
    const float* W_abn       = (const float*)d_in[8];
    const float* b_abn       = (const float*)d_in[9];
    const float* W_org       = (const float*)d_in[10];
    const float* b_org       = (const float*)d_in[11];
    const float* D           = (const float*)d_in[12];
    const float* W_o2a       = (const float*)d_in[13];
    const float* b_o2a       = (const float*)d_in[14];
    const int* lab_idx     = (const int*)d_in[16];
    const int* lab_org_idx = (const int*)d_in[17];
    const int* abn_idx     = (const int*)d_in[18];
    const int* abn_org_idx = (const int*)d_in[19];
    const int* o2a_abn_idx = (const int*)d_in[20];
    const int* o2a_org_idx = (const int*)d_in[21];
    char* ws = (char*)d_ws;
    float* out = (float*)d_out;

    pk_pre<<<465, 256, 0, stream>>>(W_lab, W_abn, D, W_org, W_o2a, lab_rel,
                                    lab_idx, lab_org_idx, abn_idx, abn_org_idx,
                                    o2a_abn_idx, o2a_org_idx, ws);
    pk_bias2<<<18, 256, 0, stream>>>(lab_concept, abn_concept, lab_rel, abn_rel,
                                     b_lab, b_abn, lab_idx, abn_idx, ws);
    kg_main<<<NBT, 256, 0, stream>>>(lab_feats, abn_feats, b_org, b_o2a, ws, out);
}